// Round 1
// baseline (800.842 us; speedup 1.0000x reference)
//
#include <hip/hip_runtime.h>

#define NB 4
#define NPTS 8192
#define DD 64
#define TILE 32
#define HALO 8
#define HPTS (TILE + 2*HALO)   // 48

// out[b,i,:] = [max_j h4 (0:64), max_j h3 (64:128), max_j h2 (128:192),
//               max_j h1 (192:256), x_i (256:320)]
__global__ __launch_bounds__(256, 2) void oec_kernel(
    const float* __restrict__ x,     // (B,N,64)
    const float* __restrict__ W1,    // (192,64) row-major
    const float* __restrict__ b1,
    const float* __restrict__ W2,    // (128,64)
    const float* __restrict__ b2,
    const float* __restrict__ W3,    // (192,64)
    const float* __restrict__ b3,
    const float* __restrict__ W4,    // (256,64)
    const float* __restrict__ b4,
    float* __restrict__ out)         // (B,N,320)
{
    __shared__ float smX[HPTS][DD];     // 12 KB
    __shared__ float smC[HPTS][DD];     // 12 KB  c_p = x_p @ (W1b - W1c)
    __shared__ float smD[HPTS][DD];     // 12 KB  d_p = x_p @ (W1b + W1c)
    __shared__ float smH1[4][8][DD];    // 8 KB per-wave h1 staging
    __shared__ float smH2[4][8][DD];    // 8 KB
    __shared__ float smH3[4][8][DD];    // 8 KB   -> total 60 KB

    const int tid = threadIdx.x;
    const int wv  = tid >> 6;
    const int ln  = tid & 63;
    const int blocksPerB = NPTS / TILE;          // 256
    const int b  = blockIdx.x / blocksPerB;
    const int p0 = (blockIdx.x % blocksPerB) * TILE;

    const float* xb = x + (size_t)b * NPTS * DD;

    // ---- phase 1: stage x tile + halo ----
    for (int idx = tid; idx < HPTS * DD; idx += 256) {
        int r = idx >> 6;
        int d = idx & 63;
        int gp = p0 - HALO + r;
        gp = min(max(gp, 0), NPTS - 1);
        smX[r][d] = xb[(size_t)gp * DD + d];
    }
    __syncthreads();

    // ---- phase 2: neighbor-role vectors c,d for all halo points ----
    for (int p = wv; p < HPTS; p += 4) {
        float accc = 0.f, accd = 0.f;
        for (int d4 = 0; d4 < DD; d4 += 4) {
            float4 xv = *(const float4*)&smX[p][d4];
            float xs[4] = {xv.x, xv.y, xv.z, xv.w};
            #pragma unroll
            for (int q = 0; q < 4; ++q) {
                int d = d4 + q;
                float wb = W1[(64  + d) * 64 + ln];
                float wc = W1[(128 + d) * 64 + ln];
                accc += xs[q] * (wb - wc);
                accd += xs[q] * (wb + wc);
            }
        }
        smC[p][ln] = accc;
        smD[p][ln] = accd;
    }
    __syncthreads();

    const float bias1 = b1[ln];
    const float bias2 = b2[ln];
    const float bias3 = b3[ln];
    const float bias4 = b4[ln];

    // ---- phase 3: per-point edge loop; wave wv owns local points wv*8..wv*8+7 ----
    for (int it = 0; it < TILE / 4; ++it) {
        const int iloc = wv * (TILE / 4) + it;
        const int i    = p0 + iloc;
        const int ih   = iloc + HALO;

        // center precompute: a = x@(W1a+W1c), b = x@(W1a-W1c),
        // e = b2 + x@W2[64:], f = b3 + x@W3[128:], g = b4 + x@W4[192:]
        float a_ = 0.f, b_ = 0.f, e_ = bias2, f_ = bias3, g_ = bias4;
        for (int d4 = 0; d4 < DD; d4 += 4) {
            float4 xv = *(const float4*)&smX[ih][d4];
            float xs[4] = {xv.x, xv.y, xv.z, xv.w};
            #pragma unroll
            for (int q = 0; q < 4; ++q) {
                int d = d4 + q;
                float wa = W1[d * 64 + ln];
                float wc = W1[(128 + d) * 64 + ln];
                a_ += xs[q] * (wa + wc);
                b_ += xs[q] * (wa - wc);
                e_ += xs[q] * W2[(64  + d) * 64 + ln];
                f_ += xs[q] * W3[(128 + d) * 64 + ln];
                g_ += xs[q] * W4[(192 + d) * 64 + ln];
            }
        }

        float mx1 = -1e30f, mx2 = -1e30f, mx3 = -1e30f, mx4 = -1e30f;

        for (int grp = 0; grp < 2; ++grp) {
            // ---- h1: adds only ----
            #pragma unroll
            for (int j = 0; j < 8; ++j) {
                int off = (grp == 0) ? (j + 1) : -(j + 1);
                int n = i + off;
                n = min(max(n, 0), NPTS - 1);
                int nl = n - p0 + HALO;
                float h1 = (grp == 0 ? (a_ + smC[nl][ln]) : (b_ + smD[nl][ln])) + bias1;
                h1 = fmaxf(h1, 0.f);
                mx1 = fmaxf(mx1, h1);
                smH1[wv][j][ln] = h1;
            }
            __syncthreads();

            // ---- layer 2: h2 = relu(h1@W2a + e) ----
            {
                float acc[8];
                #pragma unroll
                for (int j = 0; j < 8; ++j) acc[j] = 0.f;
                for (int d4 = 0; d4 < DD; d4 += 4) {
                    float w0 = W2[(d4 + 0) * 64 + ln];
                    float w1 = W2[(d4 + 1) * 64 + ln];
                    float w2 = W2[(d4 + 2) * 64 + ln];
                    float w3 = W2[(d4 + 3) * 64 + ln];
                    #pragma unroll
                    for (int j = 0; j < 8; ++j) {
                        float4 h = *(const float4*)&smH1[wv][j][d4];
                        acc[j] += h.x * w0 + h.y * w1 + h.z * w2 + h.w * w3;
                    }
                }
                #pragma unroll
                for (int j = 0; j < 8; ++j) {
                    float h2v = fmaxf(acc[j] + e_, 0.f);
                    mx2 = fmaxf(mx2, h2v);
                    smH2[wv][j][ln] = h2v;
                }
            }
            __syncthreads();

            // ---- layer 3: h3 = relu(h2@W3a + h1@W3b + f) ----
            {
                float acc[8];
                #pragma unroll
                for (int j = 0; j < 8; ++j) acc[j] = 0.f;
                for (int d4 = 0; d4 < DD; d4 += 4) {
                    float wa0 = W3[(d4 + 0) * 64 + ln];
                    float wa1 = W3[(d4 + 1) * 64 + ln];
                    float wa2 = W3[(d4 + 2) * 64 + ln];
                    float wa3 = W3[(d4 + 3) * 64 + ln];
                    float wb0 = W3[(64 + d4 + 0) * 64 + ln];
                    float wb1 = W3[(64 + d4 + 1) * 64 + ln];
                    float wb2 = W3[(64 + d4 + 2) * 64 + ln];
                    float wb3 = W3[(64 + d4 + 3) * 64 + ln];
                    #pragma unroll
                    for (int j = 0; j < 8; ++j) {
                        float4 h2v = *(const float4*)&smH2[wv][j][d4];
                        float4 h1v = *(const float4*)&smH1[wv][j][d4];
                        acc[j] += h2v.x * wa0 + h2v.y * wa1 + h2v.z * wa2 + h2v.w * wa3
                                + h1v.x * wb0 + h1v.y * wb1 + h1v.z * wb2 + h1v.w * wb3;
                    }
                }
                #pragma unroll
                for (int j = 0; j < 8; ++j) {
                    float h3v = fmaxf(acc[j] + f_, 0.f);
                    mx3 = fmaxf(mx3, h3v);
                    smH3[wv][j][ln] = h3v;
                }
            }
            __syncthreads();

            // ---- layer 4: h4 = h3@W4a + h2@W4b + h1@W4c + g (no relu) ----
            {
                float acc[8];
                #pragma unroll
                for (int j = 0; j < 8; ++j) acc[j] = 0.f;
                for (int d4 = 0; d4 < DD; d4 += 4) {
                    float wa0 = W4[(d4 + 0) * 64 + ln];
                    float wa1 = W4[(d4 + 1) * 64 + ln];
                    float wa2 = W4[(d4 + 2) * 64 + ln];
                    float wa3 = W4[(d4 + 3) * 64 + ln];
                    float wb0 = W4[(64 + d4 + 0) * 64 + ln];
                    float wb1 = W4[(64 + d4 + 1) * 64 + ln];
                    float wb2 = W4[(64 + d4 + 2) * 64 + ln];
                    float wb3 = W4[(64 + d4 + 3) * 64 + ln];
                    float wc0 = W4[(128 + d4 + 0) * 64 + ln];
                    float wc1 = W4[(128 + d4 + 1) * 64 + ln];
                    float wc2 = W4[(128 + d4 + 2) * 64 + ln];
                    float wc3 = W4[(128 + d4 + 3) * 64 + ln];
                    #pragma unroll
                    for (int j = 0; j < 8; ++j) {
                        float4 h3v = *(const float4*)&smH3[wv][j][d4];
                        float4 h2v = *(const float4*)&smH2[wv][j][d4];
                        float4 h1v = *(const float4*)&smH1[wv][j][d4];
                        acc[j] += h3v.x * wa0 + h3v.y * wa1 + h3v.z * wa2 + h3v.w * wa3
                                + h2v.x * wb0 + h2v.y * wb1 + h2v.z * wb2 + h2v.w * wb3
                                + h1v.x * wc0 + h1v.y * wc1 + h1v.z * wc2 + h1v.w * wc3;
                    }
                }
                #pragma unroll
                for (int j = 0; j < 8; ++j) {
                    float h4v = acc[j] + g_;
                    mx4 = fmaxf(mx4, h4v);
                }
            }
            __syncthreads();
        }

        // ---- write output ----
        const float xi = smX[ih][ln];
        const size_t base = ((size_t)b * NPTS + i) * 320;
        out[base +       ln] = mx4;
        out[base +  64 + ln] = mx3;
        out[base + 128 + ln] = mx2;
        out[base + 192 + ln] = mx1;
        out[base + 256 + ln] = xi;
    }
}

extern "C" void kernel_launch(void* const* d_in, const int* in_sizes, int n_in,
                              void* d_out, int out_size, void* d_ws, size_t ws_size,
                              hipStream_t stream) {
    const float* x  = (const float*)d_in[0];
    // d_in[1] = pos : unused by the reference
    const float* W1 = (const float*)d_in[2];
    const float* b1 = (const float*)d_in[3];
    const float* W2 = (const float*)d_in[4];
    const float* b2 = (const float*)d_in[5];
    const float* W3 = (const float*)d_in[6];
    const float* b3 = (const float*)d_in[7];
    const float* W4 = (const float*)d_in[8];
    const float* b4 = (const float*)d_in[9];
    float* out = (float*)d_out;

    dim3 grid(NB * (NPTS / TILE));
    oec_kernel<<<grid, 256, 0, stream>>>(x, W1, b1, W2, b2, W3, b3, W4, b4, out);
}

// Round 3
// 170.688 us; speedup vs baseline: 4.6918x; 4.6918x over previous
//
#include <hip/hip_runtime.h>

#define NB 4
#define NPTS 8192

typedef __bf16 bf16x8 __attribute__((ext_vector_type(8)));
typedef float f32x4 __attribute__((ext_vector_type(4)));

__device__ __forceinline__ float bf2f(unsigned short u) {
    union { unsigned int i; float f; } c; c.i = ((unsigned int)u) << 16; return c.f;
}
__device__ __forceinline__ unsigned short f2bf(float f) {
    union { __bf16 h; unsigned short u; } c; c.h = (__bf16)f; return c.u;
}

// ---------------- kernel 0: pack chain weights into B-frag layout (bf16) ----
// wpack frag (w, fg=u*2+ks), lane l, elem i = W[rowoff + ks*32 + 8*(l>>4) + i][16u + (l&15)]
__global__ void k0_wpack(const float* __restrict__ W2, const float* __restrict__ W3,
                         const float* __restrict__ W4, unsigned short* __restrict__ wpack)
{
    int gid = blockIdx.x * 256 + threadIdx.x;
    if (gid >= 6 * 512) return;
    int w = gid >> 9, rem = gid & 511;
    int fg = rem >> 6, l = rem & 63;
    int u = fg >> 1, ks = fg & 1;
    const float* src; int rowoff;
    switch (w) {
        case 0: src = W2; rowoff = 0;   break;  // W2a
        case 1: src = W3; rowoff = 0;   break;  // W3a
        case 2: src = W3; rowoff = 64;  break;  // W3b
        case 3: src = W4; rowoff = 0;   break;  // W4a
        case 4: src = W4; rowoff = 64;  break;  // W4b
        default: src = W4; rowoff = 128; break; // W4c
    }
    int col = 16 * u + (l & 15);
    int k0 = rowoff + ks * 32 + 8 * (l >> 4);
    union { unsigned short u16[8]; uint4 v; } pk;
    #pragma unroll
    for (int i = 0; i < 8; ++i)
        pk.u16[i] = f2bf(src[(size_t)(k0 + i) * 64 + col]);
    *(uint4*)(wpack + ((size_t)(w * 8 + fg) * 64 + l) * 8) = pk.v;
}

// ---------------- kernel 1: per-point role vectors -> P[b][n][7][64] bf16 ----
// roles: 0:a=x@(W1a+W1c) 1:b=x@(W1a-W1c) 2:c=x@(W1b-W1c) 3:d=x@(W1b+W1c)
//        4:e=x@W2b 5:f=x@W3c 6:g=x@W4d
// pairing (matches reference idx = i - offsets, offsets=[-8..-1,1..8]):
//   positive-offset neighbors (i+1..i+8): h1 = a_i + c_n + b1   (ordered = xc-knn)
//   negative-offset neighbors (i-1..i-8): h1 = b_i + d_n + b1   (ordered = knn-xc)
__global__ __launch_bounds__(256) void k1_roles(
    const float* __restrict__ x, const float* __restrict__ W1,
    const float* __restrict__ W2, const float* __restrict__ W3,
    const float* __restrict__ W4, unsigned short* __restrict__ P)
{
    __shared__ float smX[16][64];
    const int tid = threadIdx.x;
    const int bIdx = blockIdx.x >> 9;            // 512 blocks per batch
    const int p0 = (blockIdx.x & 511) * 16;
    const float* xb = x + ((size_t)bIdx * NPTS + p0) * 64;
    for (int idx = tid; idx < 16 * 64; idx += 256)
        smX[idx >> 6][idx & 63] = xb[idx];
    __syncthreads();
    const int wv = tid >> 6, ln = tid & 63;
    float acc[7][4];
    #pragma unroll
    for (int r = 0; r < 7; ++r)
        #pragma unroll
        for (int p = 0; p < 4; ++p) acc[r][p] = 0.f;
    for (int k = 0; k < 64; ++k) {
        float w1a = W1[(size_t)k * 64 + ln];
        float w1b = W1[(size_t)(64 + k) * 64 + ln];
        float w1c = W1[(size_t)(128 + k) * 64 + ln];
        float w2b = W2[(size_t)(64 + k) * 64 + ln];
        float w3c = W3[(size_t)(128 + k) * 64 + ln];
        float w4d = W4[(size_t)(192 + k) * 64 + ln];
        float wac = w1a + w1c, wamc = w1a - w1c;
        float wbmc = w1b - w1c, wbpc = w1b + w1c;
        #pragma unroll
        for (int p = 0; p < 4; ++p) {
            float xv = smX[wv * 4 + p][k];
            acc[0][p] += xv * wac;  acc[1][p] += xv * wamc;
            acc[2][p] += xv * wbmc; acc[3][p] += xv * wbpc;
            acc[4][p] += xv * w2b;  acc[5][p] += xv * w3c;  acc[6][p] += xv * w4d;
        }
    }
    #pragma unroll
    for (int p = 0; p < 4; ++p) {
        size_t base = ((size_t)bIdx * NPTS + p0 + wv * 4 + p) * 7 * 64;
        #pragma unroll
        for (int r = 0; r < 7; ++r)
            P[base + r * 64 + ln] = f2bf(acc[r][p]);
    }
}

// ---------------- kernel 2: edge chain with MFMA ----------------------------
__device__ __forceinline__ bf16x8 ldw(const unsigned short* wpack, int w, int u, int ks, int l) {
    union { uint4 v; bf16x8 b; } c;
    c.v = *(const uint4*)(wpack + ((size_t)((w * 8 + u * 2 + ks) * 64) + l) * 8);
    return c.b;
}

__global__ __launch_bounds__(256) void k2_main(
    const float* __restrict__ x,
    const float* __restrict__ b1, const float* __restrict__ b2,
    const float* __restrict__ b3, const float* __restrict__ b4,
    const unsigned short* __restrict__ wpack, const unsigned short* __restrict__ P,
    float* __restrict__ out)
{
    __shared__ unsigned short smH[4][64 * 64];   // 32 KB, per-wave swizzled h staging
    const int tid = threadIdx.x;
    const int wv = tid >> 6, l = tid & 63;
    const int g = l >> 4, s = l & 15;
    const int bIdx = blockIdx.x >> 9;
    const int p0 = (blockIdx.x & 511) * 16 + wv * 4;   // wave's first point
    const size_t pb = (size_t)bIdx * NPTS;

    unsigned short* H = smH[wv];

    // b1 in frag layout: b1v[ks][i] at ch = ks*32 + 8g + i
    float b1v[2][8];
    #pragma unroll
    for (int ks = 0; ks < 2; ++ks) {
        float4 t0 = *(const float4*)&b1[ks * 32 + 8 * g];
        float4 t1 = *(const float4*)&b1[ks * 32 + 8 * g + 4];
        b1v[ks][0] = t0.x; b1v[ks][1] = t0.y; b1v[ks][2] = t0.z; b1v[ks][3] = t0.w;
        b1v[ks][4] = t1.x; b1v[ks][5] = t1.y; b1v[ks][6] = t1.z; b1v[ks][7] = t1.w;
    }

    // per-lane edge role: edge j = s
    // s<8: positive offset s+1  -> h1 = a_i + c_n
    // s>=8: negative offset 7-s -> h1 = b_i + d_n
    const int off    = (s < 8) ? (s + 1) : (7 - s);
    const int roleAB = (s < 8) ? 0 : 1;
    const int roleCD = (s < 8) ? 2 : 3;

    // ---- build h1 A-frags: lane holds A[row=s][k=ks*32+8g+i] ----
    bf16x8 A1[4][2];
    #pragma unroll
    for (int t = 0; t < 4; ++t) {
        int ip = p0 + t;
        int n = ip + off; n = min(max(n, 0), NPTS - 1);
        const unsigned short* Pa = P + ((pb + ip) * 7 + roleAB) * 64;
        const unsigned short* Pc = P + ((pb + n) * 7 + roleCD) * 64;
        #pragma unroll
        for (int ks = 0; ks < 2; ++ks) {
            union { unsigned short u[8]; uint4 v; } va, vc;
            va.v = *(const uint4*)(Pa + ks * 32 + 8 * g);
            vc.v = *(const uint4*)(Pc + ks * 32 + 8 * g);
            union { unsigned short u[8]; bf16x8 v; } fa;
            #pragma unroll
            for (int i = 0; i < 8; ++i) {
                float h = bf2f(va.u[i]) + bf2f(vc.u[i]) + b1v[ks][i];
                fa.u[i] = f2bf(fmaxf(h, 0.f));
            }
            A1[t][ks] = fa.v;
        }
    }

    // D-layout biases: ch = 16u + s
    float b2d[4], b3d[4], b4d[4];
    #pragma unroll
    for (int u = 0; u < 4; ++u) {
        b2d[u] = b2[16 * u + s]; b3d[u] = b3[16 * u + s]; b4d[u] = b4[16 * u + s];
    }

    float mxv2[4], mxv3[4], mxv4[4];
    #pragma unroll
    for (int t = 0; t < 4; ++t) { mxv2[t] = 0.f; mxv3[t] = 0.f; mxv4[t] = 0.f; }

    // ================= layer 2: h2 = relu(h1@W2a + e + b2) =================
    #pragma unroll
    for (int u = 0; u < 4; ++u) {
        bf16x8 B0 = ldw(wpack, 0, u, 0, l);
        bf16x8 B1 = ldw(wpack, 0, u, 1, l);
        unsigned short ed[4];
        #pragma unroll
        for (int t = 0; t < 4; ++t)
            ed[t] = P[((pb + p0 + t) * 7 + 4) * 64 + 16 * u + s];
        #pragma unroll
        for (int t = 0; t < 4; ++t) {
            f32x4 acc = {0.f, 0.f, 0.f, 0.f};
            acc = __builtin_amdgcn_mfma_f32_16x16x32_bf16(A1[t][0], B0, acc, 0, 0, 0);
            acc = __builtin_amdgcn_mfma_f32_16x16x32_bf16(A1[t][1], B1, acc, 0, 0, 0);
            float eb = bf2f(ed[t]) + b2d[u];
            float m = 0.f;
            #pragma unroll
            for (int r = 0; r < 4; ++r) {
                float v = fmaxf(acc[r] + eb, 0.f);
                m = fmaxf(m, v);
                int edge = t * 16 + 4 * g + r;
                H[edge * 64 + (((16 * u + s)) ^ ((edge & 7) << 3))] = f2bf(v);
            }
            m = fmaxf(m, __shfl_xor(m, 16));
            m = fmaxf(m, __shfl_xor(m, 32));
            if (g == u) mxv2[t] = m;
        }
    }

    // read h2 A-frags
    bf16x8 A2[4][2];
    #pragma unroll
    for (int t = 0; t < 4; ++t)
        #pragma unroll
        for (int ks = 0; ks < 2; ++ks) {
            int edge = t * 16 + s;
            int ch = ks * 32 + 8 * g;
            A2[t][ks] = *(const bf16x8*)&H[edge * 64 + (ch ^ ((s & 7) << 3))];
        }

    // ================= layer 3: h3 = relu(h2@W3a + h1@W3b + f + b3) =========
    #pragma unroll
    for (int u = 0; u < 4; ++u) {
        bf16x8 Ba0 = ldw(wpack, 1, u, 0, l);
        bf16x8 Ba1 = ldw(wpack, 1, u, 1, l);
        bf16x8 Bb0 = ldw(wpack, 2, u, 0, l);
        bf16x8 Bb1 = ldw(wpack, 2, u, 1, l);
        unsigned short fd[4];
        #pragma unroll
        for (int t = 0; t < 4; ++t)
            fd[t] = P[((pb + p0 + t) * 7 + 5) * 64 + 16 * u + s];
        #pragma unroll
        for (int t = 0; t < 4; ++t) {
            f32x4 acc = {0.f, 0.f, 0.f, 0.f};
            acc = __builtin_amdgcn_mfma_f32_16x16x32_bf16(A2[t][0], Ba0, acc, 0, 0, 0);
            acc = __builtin_amdgcn_mfma_f32_16x16x32_bf16(A2[t][1], Ba1, acc, 0, 0, 0);
            acc = __builtin_amdgcn_mfma_f32_16x16x32_bf16(A1[t][0], Bb0, acc, 0, 0, 0);
            acc = __builtin_amdgcn_mfma_f32_16x16x32_bf16(A1[t][1], Bb1, acc, 0, 0, 0);
            float fb = bf2f(fd[t]) + b3d[u];
            float m = 0.f;
            #pragma unroll
            for (int r = 0; r < 4; ++r) {
                float v = fmaxf(acc[r] + fb, 0.f);
                m = fmaxf(m, v);
                int edge = t * 16 + 4 * g + r;
                H[edge * 64 + (((16 * u + s)) ^ ((edge & 7) << 3))] = f2bf(v);
            }
            m = fmaxf(m, __shfl_xor(m, 16));
            m = fmaxf(m, __shfl_xor(m, 32));
            if (g == u) mxv3[t] = m;
        }
    }

    // read h3 A-frags
    bf16x8 A3[4][2];
    #pragma unroll
    for (int t = 0; t < 4; ++t)
        #pragma unroll
        for (int ks = 0; ks < 2; ++ks) {
            int edge = t * 16 + s;
            int ch = ks * 32 + 8 * g;
            A3[t][ks] = *(const bf16x8*)&H[edge * 64 + (ch ^ ((s & 7) << 3))];
        }

    // ================= layer 4: h4 = h3@W4a + h2@W4b + h1@W4c + g + b4 ======
    #pragma unroll
    for (int u = 0; u < 4; ++u) {
        bf16x8 Ba0 = ldw(wpack, 3, u, 0, l);
        bf16x8 Ba1 = ldw(wpack, 3, u, 1, l);
        bf16x8 Bb0 = ldw(wpack, 4, u, 0, l);
        bf16x8 Bb1 = ldw(wpack, 4, u, 1, l);
        bf16x8 Bc0 = ldw(wpack, 5, u, 0, l);
        bf16x8 Bc1 = ldw(wpack, 5, u, 1, l);
        unsigned short gd[4];
        #pragma unroll
        for (int t = 0; t < 4; ++t)
            gd[t] = P[((pb + p0 + t) * 7 + 6) * 64 + 16 * u + s];
        #pragma unroll
        for (int t = 0; t < 4; ++t) {
            f32x4 acc = {0.f, 0.f, 0.f, 0.f};
            acc = __builtin_amdgcn_mfma_f32_16x16x32_bf16(A3[t][0], Ba0, acc, 0, 0, 0);
            acc = __builtin_amdgcn_mfma_f32_16x16x32_bf16(A3[t][1], Ba1, acc, 0, 0, 0);
            acc = __builtin_amdgcn_mfma_f32_16x16x32_bf16(A2[t][0], Bb0, acc, 0, 0, 0);
            acc = __builtin_amdgcn_mfma_f32_16x16x32_bf16(A2[t][1], Bb1, acc, 0, 0, 0);
            acc = __builtin_amdgcn_mfma_f32_16x16x32_bf16(A1[t][0], Bc0, acc, 0, 0, 0);
            acc = __builtin_amdgcn_mfma_f32_16x16x32_bf16(A1[t][1], Bc1, acc, 0, 0, 0);
            float gb = bf2f(gd[t]) + b4d[u];
            float m = -3.0e38f;
            #pragma unroll
            for (int r = 0; r < 4; ++r)
                m = fmaxf(m, acc[r] + gb);
            m = fmaxf(m, __shfl_xor(m, 16));
            m = fmaxf(m, __shfl_xor(m, 32));
            if (g == u) mxv4[t] = m;
        }
    }

    // ================= mx1 via sliding-window max (ch = lane) ===============
    // positive side: c over [p0+1, p0+11] (clip high); negative: d over [p0-8, p0+2] (clip low)
    float cr[11], dr[11];
    #pragma unroll
    for (int k = 0; k < 11; ++k) {
        int nc = min(p0 + 1 + k, NPTS - 1);
        int nd = max(p0 - 8 + k, 0);
        cr[k] = bf2f(P[((pb + nc) * 7 + 2) * 64 + l]);
        dr[k] = bf2f(P[((pb + nd) * 7 + 3) * 64 + l]);
    }
    float m2c[10], m2d[10];
    #pragma unroll
    for (int k = 0; k < 10; ++k) { m2c[k] = fmaxf(cr[k], cr[k + 1]); m2d[k] = fmaxf(dr[k], dr[k + 1]); }
    float m4c[8], m4d[8];
    #pragma unroll
    for (int k = 0; k < 8; ++k) { m4c[k] = fmaxf(m2c[k], m2c[k + 2]); m4d[k] = fmaxf(m2d[k], m2d[k + 2]); }
    const float b1l = b1[l];

    #pragma unroll
    for (int t = 0; t < 4; ++t) {
        float mxc = fmaxf(m4c[t], m4c[t + 4]);   // max c[i+1..i+8], i = p0+t
        float mxd = fmaxf(m4d[t], m4d[t + 4]);   // max d[i-8..i-1]
        float av = bf2f(P[((pb + p0 + t) * 7 + 0) * 64 + l]);
        float bv = bf2f(P[((pb + p0 + t) * 7 + 1) * 64 + l]);
        float mx1 = fmaxf(fmaxf(av + mxc, bv + mxd) + b1l, 0.f);
        float xi = x[(pb + p0 + t) * 64 + l];
        size_t ob = (pb + p0 + t) * 320;
        out[ob +       l] = mxv4[t];
        out[ob +  64 + l] = mxv3[t];
        out[ob + 128 + l] = mxv2[t];
        out[ob + 192 + l] = mx1;
        out[ob + 256 + l] = xi;
    }
}

extern "C" void kernel_launch(void* const* d_in, const int* in_sizes, int n_in,
                              void* d_out, int out_size, void* d_ws, size_t ws_size,
                              hipStream_t stream) {
    const float* x  = (const float*)d_in[0];
    // d_in[1] = pos : unused by the reference
    const float* W1 = (const float*)d_in[2];
    const float* b1 = (const float*)d_in[3];
    const float* W2 = (const float*)d_in[4];
    const float* b2 = (const float*)d_in[5];
    const float* W3 = (const float*)d_in[6];
    const float* b3 = (const float*)d_in[7];
    const float* W4 = (const float*)d_in[8];
    const float* b4 = (const float*)d_in[9];
    float* out = (float*)d_out;

    unsigned short* wpack = (unsigned short*)d_ws;                  // 48 KB
    unsigned short* P     = (unsigned short*)((char*)d_ws + 65536); // 29.4 MB

    k0_wpack<<<12, 256, 0, stream>>>(W2, W3, W4, wpack);
    k1_roles<<<NB * (NPTS / 16), 256, 0, stream>>>(x, W1, W2, W3, W4, P);
    k2_main<<<NB * (NPTS / 16), 256, 0, stream>>>(x, b1, b2, b3, b4, wpack, P, out);
}

// Round 5
// 145.596 us; speedup vs baseline: 5.5004x; 1.1723x over previous
//
#include <hip/hip_runtime.h>

#define NB 4
#define NPTS 8192

typedef __bf16 bf16x8 __attribute__((ext_vector_type(8)));
typedef float f32x4 __attribute__((ext_vector_type(4)));

__device__ __forceinline__ float bf2f(unsigned short u) {
    union { unsigned int i; float f; } c; c.i = ((unsigned int)u) << 16; return c.f;
}
__device__ __forceinline__ unsigned short f2bf(float f) {
    union { __bf16 h; unsigned short u; } c; c.h = (__bf16)f; return c.u;
}

// ---------------- kernel 0: pack weights into B-frag layout (bf16) ----------
// Part A (gid < 3072): chain weights wpack, frag (w, fg=u*2+ks):
//   lane l, elem i = W[rowoff + ks*32 + 8*(l>>4) + i][16u + (l&15)]
// Part B (gid >= 3072): role weights w7, frag (r, u, ks), fi=(r*4+u)*2+ks:
//   roles 0:W1a+W1c 1:W1a-W1c 2:W1b-W1c 3:W1b+W1c 4:W2b 5:W3c 6:W4d
__global__ void k0_wpack(const float* __restrict__ W1, const float* __restrict__ W2,
                         const float* __restrict__ W3, const float* __restrict__ W4,
                         unsigned short* __restrict__ wpack, unsigned short* __restrict__ w7)
{
    int gid = blockIdx.x * 256 + threadIdx.x;
    if (gid < 3072) {
        int w = gid >> 9, rem = gid & 511;
        int fg = rem >> 6, l = rem & 63;
        int u = fg >> 1, ks = fg & 1;
        const float* src; int rowoff;
        switch (w) {
            case 0: src = W2; rowoff = 0;   break;  // W2a
            case 1: src = W3; rowoff = 0;   break;  // W3a
            case 2: src = W3; rowoff = 64;  break;  // W3b
            case 3: src = W4; rowoff = 0;   break;  // W4a
            case 4: src = W4; rowoff = 64;  break;  // W4b
            default: src = W4; rowoff = 128; break; // W4c
        }
        int col = 16 * u + (l & 15);
        int k0 = rowoff + ks * 32 + 8 * (l >> 4);
        union { unsigned short u16[8]; uint4 v; } pk;
        #pragma unroll
        for (int i = 0; i < 8; ++i)
            pk.u16[i] = f2bf(src[(size_t)(k0 + i) * 64 + col]);
        *(uint4*)(wpack + ((size_t)(w * 8 + fg) * 64 + l) * 8) = pk.v;
    } else if (gid < 3072 + 3584) {
        int t = gid - 3072;
        int fi = t >> 6, l = t & 63;
        int r = fi >> 3, uks = fi & 7;
        int u = uks >> 1, ks = uks & 1;
        int col = 16 * u + (l & 15);
        int k0 = ks * 32 + 8 * (l >> 4);
        union { unsigned short u16[8]; uint4 v; } pk;
        #pragma unroll
        for (int i = 0; i < 8; ++i) {
            int k = k0 + i;
            float v;
            switch (r) {
                case 0: v = W1[(size_t)k * 64 + col] + W1[(size_t)(128 + k) * 64 + col]; break;
                case 1: v = W1[(size_t)k * 64 + col] - W1[(size_t)(128 + k) * 64 + col]; break;
                case 2: v = W1[(size_t)(64 + k) * 64 + col] - W1[(size_t)(128 + k) * 64 + col]; break;
                case 3: v = W1[(size_t)(64 + k) * 64 + col] + W1[(size_t)(128 + k) * 64 + col]; break;
                case 4: v = W2[(size_t)(64 + k) * 64 + col]; break;
                case 5: v = W3[(size_t)(128 + k) * 64 + col]; break;
                default: v = W4[(size_t)(192 + k) * 64 + col]; break;
            }
            pk.u16[i] = f2bf(v);
        }
        *(uint4*)(w7 + ((size_t)fi * 64 + l) * 8) = pk.v;
    }
}

// ---------------- kernel 1: role vectors via MFMA -> P[b][n][7][64] bf16 ----
// wave = 16 points (one m-tile); 7 roles x 4 u-tiles x 2 k-frags = 56 MFMAs
__device__ __forceinline__ bf16x8 ldfrag(const unsigned short* base, int fi, int l) {
    union { uint4 v; bf16x8 b; } c;
    c.v = *(const uint4*)(base + ((size_t)fi * 64 + l) * 8);
    return c.b;
}

__global__ __launch_bounds__(256) void k1_mfma(
    const float* __restrict__ x, const unsigned short* __restrict__ w7,
    unsigned short* __restrict__ P)
{
    const int tid = threadIdx.x;
    const int wv = tid >> 6, l = tid & 63;
    const int g = l >> 4, s = l & 15;
    const int bIdx = blockIdx.x >> 7;                      // 128 blocks per batch
    const int p0 = ((blockIdx.x & 127) * 4 + wv) * 16;     // wave's first point
    const size_t pb = (size_t)bIdx * NPTS;

    // A-frags: lane holds x[p0+s][ks*32+8g+i]
    bf16x8 A[2];
    const float* xr = x + (pb + p0 + s) * 64;
    #pragma unroll
    for (int ks = 0; ks < 2; ++ks) {
        float4 v0 = *(const float4*)&xr[ks * 32 + 8 * g];
        float4 v1 = *(const float4*)&xr[ks * 32 + 8 * g + 4];
        union { unsigned short u[8]; bf16x8 b; } fa;
        fa.u[0] = f2bf(v0.x); fa.u[1] = f2bf(v0.y); fa.u[2] = f2bf(v0.z); fa.u[3] = f2bf(v0.w);
        fa.u[4] = f2bf(v1.x); fa.u[5] = f2bf(v1.y); fa.u[6] = f2bf(v1.z); fa.u[7] = f2bf(v1.w);
        A[ks] = fa.b;
    }

    #pragma unroll
    for (int r = 0; r < 7; ++r) {
        #pragma unroll
        for (int u = 0; u < 4; ++u) {
            int fi = (r * 4 + u) * 2;
            bf16x8 B0 = ldfrag(w7, fi, l);
            bf16x8 B1 = ldfrag(w7, fi + 1, l);
            f32x4 acc = {0.f, 0.f, 0.f, 0.f};
            acc = __builtin_amdgcn_mfma_f32_16x16x32_bf16(A[0], B0, acc, 0, 0, 0);
            acc = __builtin_amdgcn_mfma_f32_16x16x32_bf16(A[1], B1, acc, 0, 0, 0);
            // D: reg q -> point p0 + 4g + q, channel 16u + s
            #pragma unroll
            for (int q = 0; q < 4; ++q)
                P[(pb + p0 + 4 * g + q) * 448 + r * 64 + 16 * u + s] = f2bf(acc[q]);
        }
    }
}

// ---------------- kernel 2: edge chain with MFMA ----------------------------
__device__ __forceinline__ bf16x8 ldw(const unsigned short* wpack, int w, int u, int ks, int l) {
    union { uint4 v; bf16x8 b; } c;
    c.v = *(const uint4*)(wpack + ((size_t)((w * 8 + u * 2 + ks) * 64) + l) * 8);
    return c.b;
}

__global__ __launch_bounds__(256) void k2_main(
    const float* __restrict__ x,
    const float* __restrict__ b1, const float* __restrict__ b2,
    const float* __restrict__ b3, const float* __restrict__ b4,
    const unsigned short* __restrict__ wpack, const unsigned short* __restrict__ P,
    float* __restrict__ out)
{
    __shared__ unsigned short smH[4][64 * 64];   // 32 KB, per-wave swizzled h staging
    const int tid = threadIdx.x;
    const int wv = tid >> 6, l = tid & 63;
    const int g = l >> 4, s = l & 15;
    const int bIdx = blockIdx.x >> 9;
    const int p0 = (blockIdx.x & 511) * 16 + wv * 4;   // wave's first point
    const size_t pb = (size_t)bIdx * NPTS;

    unsigned short* H = smH[wv];

    // b1 in frag layout: b1v[ks][i] at ch = ks*32 + 8g + i
    float b1v[2][8];
    #pragma unroll
    for (int ks = 0; ks < 2; ++ks) {
        float4 t0 = *(const float4*)&b1[ks * 32 + 8 * g];
        float4 t1 = *(const float4*)&b1[ks * 32 + 8 * g + 4];
        b1v[ks][0] = t0.x; b1v[ks][1] = t0.y; b1v[ks][2] = t0.z; b1v[ks][3] = t0.w;
        b1v[ks][4] = t1.x; b1v[ks][5] = t1.y; b1v[ks][6] = t1.z; b1v[ks][7] = t1.w;
    }

    // per-lane edge role: edge j = s
    // s<8: positive offset s+1  -> h1 = a_i + c_n
    // s>=8: negative offset 7-s -> h1 = b_i + d_n
    const int off    = (s < 8) ? (s + 1) : (7 - s);
    const int roleAB = (s < 8) ? 0 : 1;
    const int roleCD = (s < 8) ? 2 : 3;

    // ---- build h1 A-frags: lane holds A[row=s][k=ks*32+8g+i] ----
    bf16x8 A1[4][2];
    #pragma unroll
    for (int t = 0; t < 4; ++t) {
        int ip = p0 + t;
        int n = ip + off; n = min(max(n, 0), NPTS - 1);
        const unsigned short* Pa = P + ((pb + ip) * 7 + roleAB) * 64;
        const unsigned short* Pc = P + ((pb + n) * 7 + roleCD) * 64;
        #pragma unroll
        for (int ks = 0; ks < 2; ++ks) {
            union { unsigned short u[8]; uint4 v; } va, vc;
            va.v = *(const uint4*)(Pa + ks * 32 + 8 * g);
            vc.v = *(const uint4*)(Pc + ks * 32 + 8 * g);
            union { unsigned short u[8]; bf16x8 v; } fa;
            #pragma unroll
            for (int i = 0; i < 8; ++i) {
                float h = bf2f(va.u[i]) + bf2f(vc.u[i]) + b1v[ks][i];
                fa.u[i] = f2bf(fmaxf(h, 0.f));
            }
            A1[t][ks] = fa.v;
        }
    }

    // D-layout biases: ch = 16u + s
    float b2d[4], b3d[4], b4d[4];
    #pragma unroll
    for (int u = 0; u < 4; ++u) {
        b2d[u] = b2[16 * u + s]; b3d[u] = b3[16 * u + s]; b4d[u] = b4[16 * u + s];
    }

    float mxv2[4], mxv3[4], mxv4[4];
    #pragma unroll
    for (int t = 0; t < 4; ++t) { mxv2[t] = 0.f; mxv3[t] = 0.f; mxv4[t] = 0.f; }

    // ================= layer 2: h2 = relu(h1@W2a + e + b2) =================
    #pragma unroll
    for (int u = 0; u < 4; ++u) {
        bf16x8 B0 = ldw(wpack, 0, u, 0, l);
        bf16x8 B1 = ldw(wpack, 0, u, 1, l);
        unsigned short ed[4];
        #pragma unroll
        for (int t = 0; t < 4; ++t)
            ed[t] = P[((pb + p0 + t) * 7 + 4) * 64 + 16 * u + s];
        #pragma unroll
        for (int t = 0; t < 4; ++t) {
            f32x4 acc = {0.f, 0.f, 0.f, 0.f};
            acc = __builtin_amdgcn_mfma_f32_16x16x32_bf16(A1[t][0], B0, acc, 0, 0, 0);
            acc = __builtin_amdgcn_mfma_f32_16x16x32_bf16(A1[t][1], B1, acc, 0, 0, 0);
            float eb = bf2f(ed[t]) + b2d[u];
            float m = 0.f;
            #pragma unroll
            for (int r = 0; r < 4; ++r) {
                float v = fmaxf(acc[r] + eb, 0.f);
                m = fmaxf(m, v);
                int edge = t * 16 + 4 * g + r;
                H[edge * 64 + (((16 * u + s)) ^ ((edge & 7) << 3))] = f2bf(v);
            }
            m = fmaxf(m, __shfl_xor(m, 16));
            m = fmaxf(m, __shfl_xor(m, 32));
            if (g == u) mxv2[t] = m;
        }
    }

    // read h2 A-frags
    bf16x8 A2[4][2];
    #pragma unroll
    for (int t = 0; t < 4; ++t)
        #pragma unroll
        for (int ks = 0; ks < 2; ++ks) {
            int edge = t * 16 + s;
            int ch = ks * 32 + 8 * g;
            A2[t][ks] = *(const bf16x8*)&H[edge * 64 + (ch ^ ((s & 7) << 3))];
        }

    // ================= layer 3: h3 = relu(h2@W3a + h1@W3b + f + b3) =========
    #pragma unroll
    for (int u = 0; u < 4; ++u) {
        bf16x8 Ba0 = ldw(wpack, 1, u, 0, l);
        bf16x8 Ba1 = ldw(wpack, 1, u, 1, l);
        bf16x8 Bb0 = ldw(wpack, 2, u, 0, l);
        bf16x8 Bb1 = ldw(wpack, 2, u, 1, l);
        unsigned short fd[4];
        #pragma unroll
        for (int t = 0; t < 4; ++t)
            fd[t] = P[((pb + p0 + t) * 7 + 5) * 64 + 16 * u + s];
        #pragma unroll
        for (int t = 0; t < 4; ++t) {
            f32x4 acc = {0.f, 0.f, 0.f, 0.f};
            acc = __builtin_amdgcn_mfma_f32_16x16x32_bf16(A2[t][0], Ba0, acc, 0, 0, 0);
            acc = __builtin_amdgcn_mfma_f32_16x16x32_bf16(A2[t][1], Ba1, acc, 0, 0, 0);
            acc = __builtin_amdgcn_mfma_f32_16x16x32_bf16(A1[t][0], Bb0, acc, 0, 0, 0);
            acc = __builtin_amdgcn_mfma_f32_16x16x32_bf16(A1[t][1], Bb1, acc, 0, 0, 0);
            float fb = bf2f(fd[t]) + b3d[u];
            float m = 0.f;
            #pragma unroll
            for (int r = 0; r < 4; ++r) {
                float v = fmaxf(acc[r] + fb, 0.f);
                m = fmaxf(m, v);
                int edge = t * 16 + 4 * g + r;
                H[edge * 64 + (((16 * u + s)) ^ ((edge & 7) << 3))] = f2bf(v);
            }
            m = fmaxf(m, __shfl_xor(m, 16));
            m = fmaxf(m, __shfl_xor(m, 32));
            if (g == u) mxv3[t] = m;
        }
    }

    // read h3 A-frags
    bf16x8 A3[4][2];
    #pragma unroll
    for (int t = 0; t < 4; ++t)
        #pragma unroll
        for (int ks = 0; ks < 2; ++ks) {
            int edge = t * 16 + s;
            int ch = ks * 32 + 8 * g;
            A3[t][ks] = *(const bf16x8*)&H[edge * 64 + (ch ^ ((s & 7) << 3))];
        }

    // ================= layer 4: h4 = h3@W4a + h2@W4b + h1@W4c + g + b4 ======
    #pragma unroll
    for (int u = 0; u < 4; ++u) {
        bf16x8 Ba0 = ldw(wpack, 3, u, 0, l);
        bf16x8 Ba1 = ldw(wpack, 3, u, 1, l);
        bf16x8 Bb0 = ldw(wpack, 4, u, 0, l);
        bf16x8 Bb1 = ldw(wpack, 4, u, 1, l);
        bf16x8 Bc0 = ldw(wpack, 5, u, 0, l);
        bf16x8 Bc1 = ldw(wpack, 5, u, 1, l);
        unsigned short gd[4];
        #pragma unroll
        for (int t = 0; t < 4; ++t)
            gd[t] = P[((pb + p0 + t) * 7 + 6) * 64 + 16 * u + s];
        #pragma unroll
        for (int t = 0; t < 4; ++t) {
            f32x4 acc = {0.f, 0.f, 0.f, 0.f};
            acc = __builtin_amdgcn_mfma_f32_16x16x32_bf16(A3[t][0], Ba0, acc, 0, 0, 0);
            acc = __builtin_amdgcn_mfma_f32_16x16x32_bf16(A3[t][1], Ba1, acc, 0, 0, 0);
            acc = __builtin_amdgcn_mfma_f32_16x16x32_bf16(A2[t][0], Bb0, acc, 0, 0, 0);
            acc = __builtin_amdgcn_mfma_f32_16x16x32_bf16(A2[t][1], Bb1, acc, 0, 0, 0);
            acc = __builtin_amdgcn_mfma_f32_16x16x32_bf16(A1[t][0], Bc0, acc, 0, 0, 0);
            acc = __builtin_amdgcn_mfma_f32_16x16x32_bf16(A1[t][1], Bc1, acc, 0, 0, 0);
            float gb = bf2f(gd[t]) + b4d[u];
            float m = -3.0e38f;
            #pragma unroll
            for (int r = 0; r < 4; ++r)
                m = fmaxf(m, acc[r] + gb);
            m = fmaxf(m, __shfl_xor(m, 16));
            m = fmaxf(m, __shfl_xor(m, 32));
            if (g == u) mxv4[t] = m;
        }
    }

    // ================= mx1 via sliding-window max (ch = lane) ===============
    // positive side: c over [p0+1, p0+11] (clip high); negative: d over [p0-8, p0+2] (clip low)
    float cr[11], dr[11];
    #pragma unroll
    for (int k = 0; k < 11; ++k) {
        int nc = min(p0 + 1 + k, NPTS - 1);
        int nd = max(p0 - 8 + k, 0);
        cr[k] = bf2f(P[((pb + nc) * 7 + 2) * 64 + l]);
        dr[k] = bf2f(P[((pb + nd) * 7 + 3) * 64 + l]);
    }
    float m2c[10], m2d[10];
    #pragma unroll
    for (int k = 0; k < 10; ++k) { m2c[k] = fmaxf(cr[k], cr[k + 1]); m2d[k] = fmaxf(dr[k], dr[k + 1]); }
    float m4c[8], m4d[8];
    #pragma unroll
    for (int k = 0; k < 8; ++k) { m4c[k] = fmaxf(m2c[k], m2c[k + 2]); m4d[k] = fmaxf(m2d[k], m2d[k + 2]); }
    const float b1l = b1[l];

    #pragma unroll
    for (int t = 0; t < 4; ++t) {
        float mxc = fmaxf(m4c[t], m4c[t + 4]);   // max c[i+1..i+8], i = p0+t
        float mxd = fmaxf(m4d[t], m4d[t + 4]);   // max d[i-8..i-1]
        float av = bf2f(P[((pb + p0 + t) * 7 + 0) * 64 + l]);
        float bv = bf2f(P[((pb + p0 + t) * 7 + 1) * 64 + l]);
        float mx1 = fmaxf(fmaxf(av + mxc, bv + mxd) + b1l, 0.f);
        float xi = x[(pb + p0 + t) * 64 + l];
        size_t ob = (pb + p0 + t) * 320;
        out[ob +       l] = mxv4[t];
        out[ob +  64 + l] = mxv3[t];
        out[ob + 128 + l] = mxv2[t];
        out[ob + 192 + l] = mx1;
        out[ob + 256 + l] = xi;
    }
}

extern "C" void kernel_launch(void* const* d_in, const int* in_sizes, int n_in,
                              void* d_out, int out_size, void* d_ws, size_t ws_size,
                              hipStream_t stream) {
    const float* x  = (const float*)d_in[0];
    // d_in[1] = pos : unused by the reference
    const float* W1 = (const float*)d_in[2];
    const float* b1 = (const float*)d_in[3];
    const float* W2 = (const float*)d_in[4];
    const float* b2 = (const float*)d_in[5];
    const float* W3 = (const float*)d_in[6];
    const float* b3 = (const float*)d_in[7];
    const float* W4 = (const float*)d_in[8];
    const float* b4 = (const float*)d_in[9];
    float* out = (float*)d_out;

    unsigned short* wpack = (unsigned short*)d_ws;                   // 48 KB @ 0
    unsigned short* w7    = (unsigned short*)((char*)d_ws + 65536);  // 56 KB @ 64K
    unsigned short* P     = (unsigned short*)((char*)d_ws + 131072); // 29.4 MB @ 128K

    k0_wpack<<<26, 256, 0, stream>>>(W1, W2, W3, W4, wpack, w7);
    k1_mfma<<<NB * (NPTS / 64), 256, 0, stream>>>(x, w7, P);
    k2_main<<<NB * (NPTS / 16), 256, 0, stream>>>(x, b1, b2, b3, b4, wpack, P, out);
}

// Round 9
// 144.302 us; speedup vs baseline: 5.5498x; 1.0090x over previous
//
#include <hip/hip_runtime.h>

#define NB 4
#define NPTS 8192

typedef __bf16 bf16x8 __attribute__((ext_vector_type(8)));
typedef float f32x4 __attribute__((ext_vector_type(4)));

__device__ __forceinline__ float bf2f(unsigned short u) {
    union { unsigned int i; float f; } c; c.i = ((unsigned int)u) << 16; return c.f;
}
__device__ __forceinline__ unsigned short f2bf(float f) {
    union { __bf16 h; unsigned short u; } c; c.h = (__bf16)f; return c.u;
}

// ---------------- kernel 0: pack weights into B-frag layout (bf16) ----------
// Part A (gid < 3072): chain weights wpack, frag (w, fg=u*2+ks):
//   lane l, elem i = W[rowoff + ks*32 + 8*(l>>4) + i][16u + (l&15)]
// Part B (gid >= 3072): role weights w7, frag (r, u, ks), fi=(r*4+u)*2+ks:
//   roles 0:W1a+W1c 1:W1a-W1c 2:W1b-W1c 3:W1b+W1c 4:W2b 5:W3c 6:W4d
__global__ void k0_wpack(const float* __restrict__ W1, const float* __restrict__ W2,
                         const float* __restrict__ W3, const float* __restrict__ W4,
                         unsigned short* __restrict__ wpack, unsigned short* __restrict__ w7)
{
    int gid = blockIdx.x * 256 + threadIdx.x;
    if (gid < 3072) {
        int w = gid >> 9, rem = gid & 511;
        int fg = rem >> 6, l = rem & 63;
        int u = fg >> 1, ks = fg & 1;
        const float* src; int rowoff;
        switch (w) {
            case 0: src = W2; rowoff = 0;   break;  // W2a
            case 1: src = W3; rowoff = 0;   break;  // W3a
            case 2: src = W3; rowoff = 64;  break;  // W3b
            case 3: src = W4; rowoff = 0;   break;  // W4a
            case 4: src = W4; rowoff = 64;  break;  // W4b
            default: src = W4; rowoff = 128; break; // W4c
        }
        int col = 16 * u + (l & 15);
        int k0 = rowoff + ks * 32 + 8 * (l >> 4);
        union { unsigned short u16[8]; uint4 v; } pk;
        #pragma unroll
        for (int i = 0; i < 8; ++i)
            pk.u16[i] = f2bf(src[(size_t)(k0 + i) * 64 + col]);
        *(uint4*)(wpack + ((size_t)(w * 8 + fg) * 64 + l) * 8) = pk.v;
    } else if (gid < 3072 + 3584) {
        int t = gid - 3072;
        int fi = t >> 6, l = t & 63;
        int r = fi >> 3, uks = fi & 7;
        int u = uks >> 1, ks = uks & 1;
        int col = 16 * u + (l & 15);
        int k0 = ks * 32 + 8 * (l >> 4);
        union { unsigned short u16[8]; uint4 v; } pk;
        #pragma unroll
        for (int i = 0; i < 8; ++i) {
            int k = k0 + i;
            float v;
            switch (r) {
                case 0: v = W1[(size_t)k * 64 + col] + W1[(size_t)(128 + k) * 64 + col]; break;
                case 1: v = W1[(size_t)k * 64 + col] - W1[(size_t)(128 + k) * 64 + col]; break;
                case 2: v = W1[(size_t)(64 + k) * 64 + col] - W1[(size_t)(128 + k) * 64 + col]; break;
                case 3: v = W1[(size_t)(64 + k) * 64 + col] + W1[(size_t)(128 + k) * 64 + col]; break;
                case 4: v = W2[(size_t)(64 + k) * 64 + col]; break;
                case 5: v = W3[(size_t)(128 + k) * 64 + col]; break;
                default: v = W4[(size_t)(192 + k) * 64 + col]; break;
            }
            pk.u16[i] = f2bf(v);
        }
        *(uint4*)(w7 + ((size_t)fi * 64 + l) * 8) = pk.v;
    }
}

// ---------------- kernel 1: role vectors via MFMA -> P[b][n][7][64] bf16 ----
// wave = 16 points (one m-tile); 7 roles x 4 u-tiles x 2 k-frags = 56 MFMAs.
// D-frags staged in per-wave LDS [16][448+16 pad], then copied out as
// coalesced dwordx4 (one contiguous 896B point-row per store instruction).
__device__ __forceinline__ bf16x8 ldfrag(const unsigned short* base, int fi, int l) {
    union { uint4 v; bf16x8 b; } c;
    c.v = *(const uint4*)(base + ((size_t)fi * 64 + l) * 8);
    return c.b;
}

#define PROW 464   // 448 + 16 u16 pad: shifts each point-row by 8 banks

__global__ __launch_bounds__(256) void k1_mfma(
    const float* __restrict__ x, const unsigned short* __restrict__ w7,
    unsigned short* __restrict__ P)
{
    __shared__ unsigned short smD[4][16 * PROW];   // 58 KB
    const int tid = threadIdx.x;
    const int wv = tid >> 6, l = tid & 63;
    const int g = l >> 4, s = l & 15;
    const int bIdx = blockIdx.x >> 7;                      // 128 blocks per batch
    const int p0 = ((blockIdx.x & 127) * 4 + wv) * 16;     // wave's first point
    const size_t pb = (size_t)bIdx * NPTS;

    unsigned short* Dw = smD[wv];

    // A-frags: lane holds x[p0+s][ks*32+8g+i]
    bf16x8 A[2];
    const float* xr = x + (pb + p0 + s) * 64;
    #pragma unroll
    for (int ks = 0; ks < 2; ++ks) {
        float4 v0 = *(const float4*)&xr[ks * 32 + 8 * g];
        float4 v1 = *(const float4*)&xr[ks * 32 + 8 * g + 4];
        union { unsigned short u[8]; bf16x8 b; } fa;
        fa.u[0] = f2bf(v0.x); fa.u[1] = f2bf(v0.y); fa.u[2] = f2bf(v0.z); fa.u[3] = f2bf(v0.w);
        fa.u[4] = f2bf(v1.x); fa.u[5] = f2bf(v1.y); fa.u[6] = f2bf(v1.z); fa.u[7] = f2bf(v1.w);
        A[ks] = fa.b;
    }

    #pragma unroll
    for (int r = 0; r < 7; ++r) {
        #pragma unroll
        for (int u = 0; u < 4; ++u) {
            int fi = (r * 4 + u) * 2;
            bf16x8 B0 = ldfrag(w7, fi, l);
            bf16x8 B1 = ldfrag(w7, fi + 1, l);
            f32x4 acc = {0.f, 0.f, 0.f, 0.f};
            acc = __builtin_amdgcn_mfma_f32_16x16x32_bf16(A[0], B0, acc, 0, 0, 0);
            acc = __builtin_amdgcn_mfma_f32_16x16x32_bf16(A[1], B1, acc, 0, 0, 0);
            // D: reg q -> point-row 4g+q, channel r*64 + 16u + s
            #pragma unroll
            for (int q = 0; q < 4; ++q)
                Dw[(4 * g + q) * PROW + r * 64 + 16 * u + s] = f2bf(acc[q]);
        }
    }

    // coalesced copy-out: per point, 56 lanes x 16B = contiguous 896 B
    unsigned short* Pt = P + (pb + p0) * 448;
    if (l < 56) {
        #pragma unroll
        for (int pt = 0; pt < 16; ++pt) {
            uint4 v = *(const uint4*)&Dw[pt * PROW + l * 8];
            *(uint4*)&Pt[(size_t)pt * 448 + l * 8] = v;
        }
    }
}

// ---------------- kernel 2: edge chain with MFMA ----------------------------
__device__ __forceinline__ bf16x8 ldw(const unsigned short* wpack, int w, int u, int ks, int l) {
    union { uint4 v; bf16x8 b; } c;
    c.v = *(const uint4*)(wpack + ((size_t)((w * 8 + u * 2 + ks) * 64) + l) * 8);
    return c.b;
}

__global__ __launch_bounds__(256) void k2_main(
    const float* __restrict__ x,
    const float* __restrict__ b1, const float* __restrict__ b2,
    const float* __restrict__ b3, const float* __restrict__ b4,
    const unsigned short* __restrict__ wpack, const unsigned short* __restrict__ P,
    float* __restrict__ out)
{
    __shared__ unsigned short smH[4][64 * 64];   // 32 KB, per-wave swizzled h staging
    const int tid = threadIdx.x;
    const int wv = tid >> 6, l = tid & 63;
    const int g = l >> 4, s = l & 15;
    const int bIdx = blockIdx.x >> 9;
    const int p0 = (blockIdx.x & 511) * 16 + wv * 4;   // wave's first point
    const size_t pb = (size_t)bIdx * NPTS;

    unsigned short* H = smH[wv];

    // b1 in frag layout: b1v[ks][i] at ch = ks*32 + 8g + i
    float b1v[2][8];
    #pragma unroll
    for (int ks = 0; ks < 2; ++ks) {
        float4 t0 = *(const float4*)&b1[ks * 32 + 8 * g];
        float4 t1 = *(const float4*)&b1[ks * 32 + 8 * g + 4];
        b1v[ks][0] = t0.x; b1v[ks][1] = t0.y; b1v[ks][2] = t0.z; b1v[ks][3] = t0.w;
        b1v[ks][4] = t1.x; b1v[ks][5] = t1.y; b1v[ks][6] = t1.z; b1v[ks][7] = t1.w;
    }

    // per-lane edge role: edge j = s
    // s<8: positive offset s+1  -> h1 = a_i + c_n
    // s>=8: negative offset 7-s -> h1 = b_i + d_n
    const int off    = (s < 8) ? (s + 1) : (7 - s);
    const int roleAB = (s < 8) ? 0 : 1;
    const int roleCD = (s < 8) ? 2 : 3;

    // ---- build h1 A-frags: lane holds A[row=s][k=ks*32+8g+i] ----
    bf16x8 A1[4][2];
    #pragma unroll
    for (int t = 0; t < 4; ++t) {
        int ip = p0 + t;
        int n = ip + off; n = min(max(n, 0), NPTS - 1);
        const unsigned short* Pa = P + ((pb + ip) * 7 + roleAB) * 64;
        const unsigned short* Pc = P + ((pb + n) * 7 + roleCD) * 64;
        #pragma unroll
        for (int ks = 0; ks < 2; ++ks) {
            union { unsigned short u[8]; uint4 v; } va, vc;
            va.v = *(const uint4*)(Pa + ks * 32 + 8 * g);
            vc.v = *(const uint4*)(Pc + ks * 32 + 8 * g);
            union { unsigned short u[8]; bf16x8 v; } fa;
            #pragma unroll
            for (int i = 0; i < 8; ++i) {
                float h = bf2f(va.u[i]) + bf2f(vc.u[i]) + b1v[ks][i];
                fa.u[i] = f2bf(fmaxf(h, 0.f));
            }
            A1[t][ks] = fa.v;
        }
    }

    // D-layout biases: ch = 16u + s
    float b2d[4], b3d[4], b4d[4];
    #pragma unroll
    for (int u = 0; u < 4; ++u) {
        b2d[u] = b2[16 * u + s]; b3d[u] = b3[16 * u + s]; b4d[u] = b4[16 * u + s];
    }

    float mxv2[4], mxv3[4], mxv4[4];
    #pragma unroll
    for (int t = 0; t < 4; ++t) { mxv2[t] = 0.f; mxv3[t] = 0.f; mxv4[t] = 0.f; }

    // ================= layer 2: h2 = relu(h1@W2a + e + b2) =================
    #pragma unroll
    for (int u = 0; u < 4; ++u) {
        bf16x8 B0 = ldw(wpack, 0, u, 0, l);
        bf16x8 B1 = ldw(wpack, 0, u, 1, l);
        unsigned short ed[4];
        #pragma unroll
        for (int t = 0; t < 4; ++t)
            ed[t] = P[((pb + p0 + t) * 7 + 4) * 64 + 16 * u + s];
        #pragma unroll
        for (int t = 0; t < 4; ++t) {
            f32x4 acc = {0.f, 0.f, 0.f, 0.f};
            acc = __builtin_amdgcn_mfma_f32_16x16x32_bf16(A1[t][0], B0, acc, 0, 0, 0);
            acc = __builtin_amdgcn_mfma_f32_16x16x32_bf16(A1[t][1], B1, acc, 0, 0, 0);
            float eb = bf2f(ed[t]) + b2d[u];
            float m = 0.f;
            #pragma unroll
            for (int r = 0; r < 4; ++r) {
                float v = fmaxf(acc[r] + eb, 0.f);
                m = fmaxf(m, v);
                int edge = t * 16 + 4 * g + r;
                H[edge * 64 + (((16 * u + s)) ^ ((edge & 7) << 3))] = f2bf(v);
            }
            m = fmaxf(m, __shfl_xor(m, 16));
            m = fmaxf(m, __shfl_xor(m, 32));
            if (g == u) mxv2[t] = m;
        }
    }

    // read h2 A-frags
    bf16x8 A2[4][2];
    #pragma unroll
    for (int t = 0; t < 4; ++t)
        #pragma unroll
        for (int ks = 0; ks < 2; ++ks) {
            int edge = t * 16 + s;
            int ch = ks * 32 + 8 * g;
            A2[t][ks] = *(const bf16x8*)&H[edge * 64 + (ch ^ ((s & 7) << 3))];
        }

    // ================= layer 3: h3 = relu(h2@W3a + h1@W3b + f + b3) =========
    #pragma unroll
    for (int u = 0; u < 4; ++u) {
        bf16x8 Ba0 = ldw(wpack, 1, u, 0, l);
        bf16x8 Ba1 = ldw(wpack, 1, u, 1, l);
        bf16x8 Bb0 = ldw(wpack, 2, u, 0, l);
        bf16x8 Bb1 = ldw(wpack, 2, u, 1, l);
        unsigned short fd[4];
        #pragma unroll
        for (int t = 0; t < 4; ++t)
            fd[t] = P[((pb + p0 + t) * 7 + 5) * 64 + 16 * u + s];
        #pragma unroll
        for (int t = 0; t < 4; ++t) {
            f32x4 acc = {0.f, 0.f, 0.f, 0.f};
            acc = __builtin_amdgcn_mfma_f32_16x16x32_bf16(A2[t][0], Ba0, acc, 0, 0, 0);
            acc = __builtin_amdgcn_mfma_f32_16x16x32_bf16(A2[t][1], Ba1, acc, 0, 0, 0);
            acc = __builtin_amdgcn_mfma_f32_16x16x32_bf16(A1[t][0], Bb0, acc, 0, 0, 0);
            acc = __builtin_amdgcn_mfma_f32_16x16x32_bf16(A1[t][1], Bb1, acc, 0, 0, 0);
            float fb = bf2f(fd[t]) + b3d[u];
            float m = 0.f;
            #pragma unroll
            for (int r = 0; r < 4; ++r) {
                float v = fmaxf(acc[r] + fb, 0.f);
                m = fmaxf(m, v);
                int edge = t * 16 + 4 * g + r;
                H[edge * 64 + (((16 * u + s)) ^ ((edge & 7) << 3))] = f2bf(v);
            }
            m = fmaxf(m, __shfl_xor(m, 16));
            m = fmaxf(m, __shfl_xor(m, 32));
            if (g == u) mxv3[t] = m;
        }
    }

    // read h3 A-frags
    bf16x8 A3[4][2];
    #pragma unroll
    for (int t = 0; t < 4; ++t)
        #pragma unroll
        for (int ks = 0; ks < 2; ++ks) {
            int edge = t * 16 + s;
            int ch = ks * 32 + 8 * g;
            A3[t][ks] = *(const bf16x8*)&H[edge * 64 + (ch ^ ((s & 7) << 3))];
        }

    // ================= layer 4: h4 = h3@W4a + h2@W4b + h1@W4c + g + b4 ======
    #pragma unroll
    for (int u = 0; u < 4; ++u) {
        bf16x8 Ba0 = ldw(wpack, 3, u, 0, l);
        bf16x8 Ba1 = ldw(wpack, 3, u, 1, l);
        bf16x8 Bb0 = ldw(wpack, 4, u, 0, l);
        bf16x8 Bb1 = ldw(wpack, 4, u, 1, l);
        bf16x8 Bc0 = ldw(wpack, 5, u, 0, l);
        bf16x8 Bc1 = ldw(wpack, 5, u, 1, l);
        unsigned short gd[4];
        #pragma unroll
        for (int t = 0; t < 4; ++t)
            gd[t] = P[((pb + p0 + t) * 7 + 6) * 64 + 16 * u + s];
        #pragma unroll
        for (int t = 0; t < 4; ++t) {
            f32x4 acc = {0.f, 0.f, 0.f, 0.f};
            acc = __builtin_amdgcn_mfma_f32_16x16x32_bf16(A3[t][0], Ba0, acc, 0, 0, 0);
            acc = __builtin_amdgcn_mfma_f32_16x16x32_bf16(A3[t][1], Ba1, acc, 0, 0, 0);
            acc = __builtin_amdgcn_mfma_f32_16x16x32_bf16(A2[t][0], Bb0, acc, 0, 0, 0);
            acc = __builtin_amdgcn_mfma_f32_16x16x32_bf16(A2[t][1], Bb1, acc, 0, 0, 0);
            acc = __builtin_amdgcn_mfma_f32_16x16x32_bf16(A1[t][0], Bc0, acc, 0, 0, 0);
            acc = __builtin_amdgcn_mfma_f32_16x16x32_bf16(A1[t][1], Bc1, acc, 0, 0, 0);
            float gb = bf2f(gd[t]) + b4d[u];
            float m = -3.0e38f;
            #pragma unroll
            for (int r = 0; r < 4; ++r)
                m = fmaxf(m, acc[r] + gb);
            m = fmaxf(m, __shfl_xor(m, 16));
            m = fmaxf(m, __shfl_xor(m, 32));
            if (g == u) mxv4[t] = m;
        }
    }

    // ================= mx1 via sliding-window max (ch = lane) ===============
    // positive side: c over [p0+1, p0+11] (clip high); negative: d over [p0-8, p0+2] (clip low)
    float cr[11], dr[11];
    #pragma unroll
    for (int k = 0; k < 11; ++k) {
        int nc = min(p0 + 1 + k, NPTS - 1);
        int nd = max(p0 - 8 + k, 0);
        cr[k] = bf2f(P[((pb + nc) * 7 + 2) * 64 + l]);
        dr[k] = bf2f(P[((pb + nd) * 7 + 3) * 64 + l]);
    }
    float m2c[10], m2d[10];
    #pragma unroll
    for (int k = 0; k < 10; ++k) { m2c[k] = fmaxf(cr[k], cr[k + 1]); m2d[k] = fmaxf(dr[k], dr[k + 1]); }
    float m4c[8], m4d[8];
    #pragma unroll
    for (int k = 0; k < 8; ++k) { m4c[k] = fmaxf(m2c[k], m2c[k + 2]); m4d[k] = fmaxf(m2d[k], m2d[k + 2]); }
    const float b1l = b1[l];

    #pragma unroll
    for (int t = 0; t < 4; ++t) {
        float mxc = fmaxf(m4c[t], m4c[t + 4]);   // max c[i+1..i+8], i = p0+t
        float mxd = fmaxf(m4d[t], m4d[t + 4]);   // max d[i-8..i-1]
        float av = bf2f(P[((pb + p0 + t) * 7 + 0) * 64 + l]);
        float bv = bf2f(P[((pb + p0 + t) * 7 + 1) * 64 + l]);
        float mx1 = fmaxf(fmaxf(av + mxc, bv + mxd) + b1l, 0.f);
        float xi = x[(pb + p0 + t) * 64 + l];
        size_t ob = (pb + p0 + t) * 320;
        out[ob +       l] = mxv4[t];
        out[ob +  64 + l] = mxv3[t];
        out[ob + 128 + l] = mxv2[t];
        out[ob + 192 + l] = mx1;
        out[ob + 256 + l] = xi;
    }
}

extern "C" void kernel_launch(void* const* d_in, const int* in_sizes, int n_in,
                              void* d_out, int out_size, void* d_ws, size_t ws_size,
                              hipStream_t stream) {
    const float* x  = (const float*)d_in[0];
    // d_in[1] = pos : unused by the reference
    const float* W1 = (const float*)d_in[2];
    const float* b1 = (const float*)d_in[3];
    const float* W2 = (const float*)d_in[4];
    const float* b2 = (const float*)d_in[5];
    const float* W3 = (const float*)d_in[6];
    const float* b3 = (const float*)d_in[7];
    const float* W4 = (const float*)d_in[8];
    const float* b4 = (const float*)d_in[9];
    float* out = (float*)d_out;

    unsigned short* wpack = (unsigned short*)d_ws;                   // 48 KB @ 0
    unsigned short* w7    = (unsigned short*)((char*)d_ws + 65536);  // 56 KB @ 64K
    unsigned short* P     = (unsigned short*)((char*)d_ws + 131072); // 29.4 MB @ 128K

    k0_wpack<<<26, 256, 0, stream>>>(W1, W2, W3, W4, wpack, w7);
    k1_mfma<<<NB * (NPTS / 64), 256, 0, stream>>>(x, w7, P);
    k2_main<<<NB * (NPTS / 16), 256, 0, stream>>>(x, b1, b2, b3, b4, wpack, P, out);
}

// Round 11
// 140.272 us; speedup vs baseline: 5.7092x; 1.0287x over previous
//
#include <hip/hip_runtime.h>

#define NB 4
#define NPTS 8192

typedef __bf16 bf16x8 __attribute__((ext_vector_type(8)));
typedef float f32x4 __attribute__((ext_vector_type(4)));

__device__ __forceinline__ float bf2f(unsigned short u) {
    union { unsigned int i; float f; } c; c.i = ((unsigned int)u) << 16; return c.f;
}
__device__ __forceinline__ unsigned short f2bf(float f) {
    union { __bf16 h; unsigned short u; } c; c.h = (__bf16)f; return c.u;
}

// ---------------- kernel 0: pack weights into B-frag layout (bf16) ----------
// Part A (gid < 3072): chain weights wpack, frag (w, fg=u*2+ks):
//   lane l, elem i = W[rowoff + ks*32 + 8*(l>>4) + i][16u + (l&15)]
// Part B (gid >= 3072): role weights w7, frag (r, u, ks), fi=(r*4+u)*2+ks:
//   roles 0:W1a+W1c 1:W1a-W1c 2:W1b-W1c 3:W1b+W1c 4:W2b 5:W3c 6:W4d
__global__ void k0_wpack(const float* __restrict__ W1, const float* __restrict__ W2,
                         const float* __restrict__ W3, const float* __restrict__ W4,
                         unsigned short* __restrict__ wpack, unsigned short* __restrict__ w7)
{
    int gid = blockIdx.x * 256 + threadIdx.x;
    if (gid < 3072) {
        int w = gid >> 9, rem = gid & 511;
        int fg = rem >> 6, l = rem & 63;
        int u = fg >> 1, ks = fg & 1;
        const float* src; int rowoff;
        switch (w) {
            case 0: src = W2; rowoff = 0;   break;  // W2a
            case 1: src = W3; rowoff = 0;   break;  // W3a
            case 2: src = W3; rowoff = 64;  break;  // W3b
            case 3: src = W4; rowoff = 0;   break;  // W4a
            case 4: src = W4; rowoff = 64;  break;  // W4b
            default: src = W4; rowoff = 128; break; // W4c
        }
        int col = 16 * u + (l & 15);
        int k0 = rowoff + ks * 32 + 8 * (l >> 4);
        union { unsigned short u16[8]; uint4 v; } pk;
        #pragma unroll
        for (int i = 0; i < 8; ++i)
            pk.u16[i] = f2bf(src[(size_t)(k0 + i) * 64 + col]);
        *(uint4*)(wpack + ((size_t)(w * 8 + fg) * 64 + l) * 8) = pk.v;
    } else if (gid < 3072 + 3584) {
        int t = gid - 3072;
        int fi = t >> 6, l = t & 63;
        int r = fi >> 3, uks = fi & 7;
        int u = uks >> 1, ks = uks & 1;
        int col = 16 * u + (l & 15);
        int k0 = ks * 32 + 8 * (l >> 4);
        union { unsigned short u16[8]; uint4 v; } pk;
        #pragma unroll
        for (int i = 0; i < 8; ++i) {
            int k = k0 + i;
            float v;
            switch (r) {
                case 0: v = W1[(size_t)k * 64 + col] + W1[(size_t)(128 + k) * 64 + col]; break;
                case 1: v = W1[(size_t)k * 64 + col] - W1[(size_t)(128 + k) * 64 + col]; break;
                case 2: v = W1[(size_t)(64 + k) * 64 + col] - W1[(size_t)(128 + k) * 64 + col]; break;
                case 3: v = W1[(size_t)(64 + k) * 64 + col] + W1[(size_t)(128 + k) * 64 + col]; break;
                case 4: v = W2[(size_t)(64 + k) * 64 + col]; break;
                case 5: v = W3[(size_t)(128 + k) * 64 + col]; break;
                default: v = W4[(size_t)(192 + k) * 64 + col]; break;
            }
            pk.u16[i] = f2bf(v);
        }
        *(uint4*)(w7 + ((size_t)fi * 64 + l) * 8) = pk.v;
    }
}

// ---------------- fused kernel: roles (in-LDS) + edge chain -----------------
__device__ __forceinline__ bf16x8 ldfrag(const unsigned short* base, int fi, int l) {
    union { uint4 v; bf16x8 b; } c;
    c.v = *(const uint4*)(base + ((size_t)fi * 64 + l) * 8);
    return c.b;
}
__device__ __forceinline__ bf16x8 ldw(const unsigned short* wpack, int w, int u, int ks, int l) {
    union { uint4 v; bf16x8 b; } c;
    c.v = *(const uint4*)(wpack + ((size_t)((w * 8 + u * 2 + ks) * 64) + l) * 8);
    return c.b;
}

#define PR 464   // roles row stride in u16 (448 + 16 pad)

__global__ __launch_bounds__(256) void k2_fused(
    const float* __restrict__ x,
    const float* __restrict__ b1, const float* __restrict__ b2,
    const float* __restrict__ b3, const float* __restrict__ b4,
    const unsigned short* __restrict__ wpack, const unsigned short* __restrict__ w7,
    float* __restrict__ out)
{
    __shared__ unsigned short Rl[32 * PR];       // 29.0 KB: roles for 32 halo points
    __shared__ unsigned short smH[4][64 * 64];   // 32 KB: per-wave swizzled h staging
    const int tid = threadIdx.x;
    const int wv = tid >> 6, l = tid & 63;
    const int g = l >> 4, s = l & 15;
    const int bIdx = blockIdx.x >> 9;
    const int p0 = (blockIdx.x & 511) * 16;      // block's first point
    const int p0w = p0 + wv * 4;                 // wave's first point
    const size_t pb = (size_t)bIdx * NPTS;

    // ======== phase A: roles for halo points [p0-8, p0+24) ========
    // 2 m-tiles x 28 (r,u) pairs; wave wv does pairs wv*7..wv*7+6 for both tiles.
    #pragma unroll
    for (int mt = 0; mt < 2; ++mt) {
        int hp = min(max(p0 - 8 + mt * 16 + s, 0), NPTS - 1);
        const float* xr = x + (pb + hp) * 64;
        bf16x8 A[2];
        #pragma unroll
        for (int ks = 0; ks < 2; ++ks) {
            float4 v0 = *(const float4*)&xr[ks * 32 + 8 * g];
            float4 v1 = *(const float4*)&xr[ks * 32 + 8 * g + 4];
            union { unsigned short u[8]; bf16x8 b; } fa;
            fa.u[0] = f2bf(v0.x); fa.u[1] = f2bf(v0.y); fa.u[2] = f2bf(v0.z); fa.u[3] = f2bf(v0.w);
            fa.u[4] = f2bf(v1.x); fa.u[5] = f2bf(v1.y); fa.u[6] = f2bf(v1.z); fa.u[7] = f2bf(v1.w);
            A[ks] = fa.b;
        }
        #pragma unroll
        for (int j = 0; j < 7; ++j) {
            int pi = wv * 7 + j;                 // (r,u) pair index
            int r = pi >> 2, u = pi & 3;
            bf16x8 B0 = ldfrag(w7, pi * 2, l);
            bf16x8 B1 = ldfrag(w7, pi * 2 + 1, l);
            f32x4 acc = {0.f, 0.f, 0.f, 0.f};
            acc = __builtin_amdgcn_mfma_f32_16x16x32_bf16(A[0], B0, acc, 0, 0, 0);
            acc = __builtin_amdgcn_mfma_f32_16x16x32_bf16(A[1], B1, acc, 0, 0, 0);
            #pragma unroll
            for (int q = 0; q < 4; ++q)
                Rl[(mt * 16 + 4 * g + q) * PR + r * 64 + 16 * u + s] = f2bf(acc[q]);
        }
    }
    __syncthreads();

    // ======== phase B: edge chain (reads roles from LDS) ========
    unsigned short* H = smH[wv];

    // b1 in frag layout: b1v[ks][i] at ch = ks*32 + 8g + i
    float b1v[2][8];
    #pragma unroll
    for (int ks = 0; ks < 2; ++ks) {
        float4 t0 = *(const float4*)&b1[ks * 32 + 8 * g];
        float4 t1 = *(const float4*)&b1[ks * 32 + 8 * g + 4];
        b1v[ks][0] = t0.x; b1v[ks][1] = t0.y; b1v[ks][2] = t0.z; b1v[ks][3] = t0.w;
        b1v[ks][4] = t1.x; b1v[ks][5] = t1.y; b1v[ks][6] = t1.z; b1v[ks][7] = t1.w;
    }

    // s<8: positive offset s+1  -> h1 = a_i + c_n
    // s>=8: negative offset 7-s -> h1 = b_i + d_n
    const int off    = (s < 8) ? (s + 1) : (7 - s);
    const int roleAB = (s < 8) ? 0 : 1;
    const int roleCD = (s < 8) ? 2 : 3;

    // ---- build h1 A-frags from LDS roles ----
    bf16x8 A1[4][2];
    #pragma unroll
    for (int t = 0; t < 4; ++t) {
        int ip = p0w + t;
        int n = min(max(ip + off, 0), NPTS - 1);
        const unsigned short* Pa = &Rl[(wv * 4 + t + 8) * PR + roleAB * 64];
        const unsigned short* Pc = &Rl[(n - p0 + 8) * PR + roleCD * 64];
        #pragma unroll
        for (int ks = 0; ks < 2; ++ks) {
            union { unsigned short u[8]; uint4 v; } va, vc;
            va.v = *(const uint4*)(Pa + ks * 32 + 8 * g);
            vc.v = *(const uint4*)(Pc + ks * 32 + 8 * g);
            union { unsigned short u[8]; bf16x8 v; } fa;
            #pragma unroll
            for (int i = 0; i < 8; ++i) {
                float h = bf2f(va.u[i]) + bf2f(vc.u[i]) + b1v[ks][i];
                fa.u[i] = f2bf(fmaxf(h, 0.f));
            }
            A1[t][ks] = fa.v;
        }
    }

    // D-layout biases: ch = 16u + s
    float b2d[4], b3d[4], b4d[4];
    #pragma unroll
    for (int u = 0; u < 4; ++u) {
        b2d[u] = b2[16 * u + s]; b3d[u] = b3[16 * u + s]; b4d[u] = b4[16 * u + s];
    }

    float mxv2[4], mxv3[4], mxv4[4];
    #pragma unroll
    for (int t = 0; t < 4; ++t) { mxv2[t] = 0.f; mxv3[t] = 0.f; mxv4[t] = 0.f; }

    // ================= layer 2: h2 = relu(h1@W2a + e + b2) =================
    #pragma unroll
    for (int u = 0; u < 4; ++u) {
        bf16x8 B0 = ldw(wpack, 0, u, 0, l);
        bf16x8 B1 = ldw(wpack, 0, u, 1, l);
        unsigned short ed[4];
        #pragma unroll
        for (int t = 0; t < 4; ++t)
            ed[t] = Rl[(wv * 4 + t + 8) * PR + 4 * 64 + 16 * u + s];
        #pragma unroll
        for (int t = 0; t < 4; ++t) {
            f32x4 acc = {0.f, 0.f, 0.f, 0.f};
            acc = __builtin_amdgcn_mfma_f32_16x16x32_bf16(A1[t][0], B0, acc, 0, 0, 0);
            acc = __builtin_amdgcn_mfma_f32_16x16x32_bf16(A1[t][1], B1, acc, 0, 0, 0);
            float eb = bf2f(ed[t]) + b2d[u];
            float m = 0.f;
            #pragma unroll
            for (int r = 0; r < 4; ++r) {
                float v = fmaxf(acc[r] + eb, 0.f);
                m = fmaxf(m, v);
                int edge = t * 16 + 4 * g + r;
                H[edge * 64 + (((16 * u + s)) ^ ((edge & 7) << 3))] = f2bf(v);
            }
            m = fmaxf(m, __shfl_xor(m, 16));
            m = fmaxf(m, __shfl_xor(m, 32));
            if (g == u) mxv2[t] = m;
        }
    }

    // read h2 A-frags
    bf16x8 A2[4][2];
    #pragma unroll
    for (int t = 0; t < 4; ++t)
        #pragma unroll
        for (int ks = 0; ks < 2; ++ks) {
            int edge = t * 16 + s;
            int ch = ks * 32 + 8 * g;
            A2[t][ks] = *(const bf16x8*)&H[edge * 64 + (ch ^ ((s & 7) << 3))];
        }

    // ================= layer 3: h3 = relu(h2@W3a + h1@W3b + f + b3) =========
    #pragma unroll
    for (int u = 0; u < 4; ++u) {
        bf16x8 Ba0 = ldw(wpack, 1, u, 0, l);
        bf16x8 Ba1 = ldw(wpack, 1, u, 1, l);
        bf16x8 Bb0 = ldw(wpack, 2, u, 0, l);
        bf16x8 Bb1 = ldw(wpack, 2, u, 1, l);
        unsigned short fd[4];
        #pragma unroll
        for (int t = 0; t < 4; ++t)
            fd[t] = Rl[(wv * 4 + t + 8) * PR + 5 * 64 + 16 * u + s];
        #pragma unroll
        for (int t = 0; t < 4; ++t) {
            f32x4 acc = {0.f, 0.f, 0.f, 0.f};
            acc = __builtin_amdgcn_mfma_f32_16x16x32_bf16(A2[t][0], Ba0, acc, 0, 0, 0);
            acc = __builtin_amdgcn_mfma_f32_16x16x32_bf16(A2[t][1], Ba1, acc, 0, 0, 0);
            acc = __builtin_amdgcn_mfma_f32_16x16x32_bf16(A1[t][0], Bb0, acc, 0, 0, 0);
            acc = __builtin_amdgcn_mfma_f32_16x16x32_bf16(A1[t][1], Bb1, acc, 0, 0, 0);
            float fb = bf2f(fd[t]) + b3d[u];
            float m = 0.f;
            #pragma unroll
            for (int r = 0; r < 4; ++r) {
                float v = fmaxf(acc[r] + fb, 0.f);
                m = fmaxf(m, v);
                int edge = t * 16 + 4 * g + r;
                H[edge * 64 + (((16 * u + s)) ^ ((edge & 7) << 3))] = f2bf(v);
            }
            m = fmaxf(m, __shfl_xor(m, 16));
            m = fmaxf(m, __shfl_xor(m, 32));
            if (g == u) mxv3[t] = m;
        }
    }

    // read h3 A-frags
    bf16x8 A3[4][2];
    #pragma unroll
    for (int t = 0; t < 4; ++t)
        #pragma unroll
        for (int ks = 0; ks < 2; ++ks) {
            int edge = t * 16 + s;
            int ch = ks * 32 + 8 * g;
            A3[t][ks] = *(const bf16x8*)&H[edge * 64 + (ch ^ ((s & 7) << 3))];
        }

    // ================= layer 4: h4 = h3@W4a + h2@W4b + h1@W4c + g + b4 ======
    #pragma unroll
    for (int u = 0; u < 4; ++u) {
        bf16x8 Ba0 = ldw(wpack, 3, u, 0, l);
        bf16x8 Ba1 = ldw(wpack, 3, u, 1, l);
        bf16x8 Bb0 = ldw(wpack, 4, u, 0, l);
        bf16x8 Bb1 = ldw(wpack, 4, u, 1, l);
        bf16x8 Bc0 = ldw(wpack, 5, u, 0, l);
        bf16x8 Bc1 = ldw(wpack, 5, u, 1, l);
        unsigned short gd[4];
        #pragma unroll
        for (int t = 0; t < 4; ++t)
            gd[t] = Rl[(wv * 4 + t + 8) * PR + 6 * 64 + 16 * u + s];
        #pragma unroll
        for (int t = 0; t < 4; ++t) {
            f32x4 acc = {0.f, 0.f, 0.f, 0.f};
            acc = __builtin_amdgcn_mfma_f32_16x16x32_bf16(A3[t][0], Ba0, acc, 0, 0, 0);
            acc = __builtin_amdgcn_mfma_f32_16x16x32_bf16(A3[t][1], Ba1, acc, 0, 0, 0);
            acc = __builtin_amdgcn_mfma_f32_16x16x32_bf16(A2[t][0], Bb0, acc, 0, 0, 0);
            acc = __builtin_amdgcn_mfma_f32_16x16x32_bf16(A2[t][1], Bb1, acc, 0, 0, 0);
            acc = __builtin_amdgcn_mfma_f32_16x16x32_bf16(A1[t][0], Bc0, acc, 0, 0, 0);
            acc = __builtin_amdgcn_mfma_f32_16x16x32_bf16(A1[t][1], Bc1, acc, 0, 0, 0);
            float gb = bf2f(gd[t]) + b4d[u];
            float m = -3.0e38f;
            #pragma unroll
            for (int r = 0; r < 4; ++r)
                m = fmaxf(m, acc[r] + gb);
            m = fmaxf(m, __shfl_xor(m, 16));
            m = fmaxf(m, __shfl_xor(m, 32));
            if (g == u) mxv4[t] = m;
        }
    }

    // ================= mx1 via sliding-window max over LDS roles ============
    float cr[11], dr[11];
    #pragma unroll
    for (int k = 0; k < 11; ++k) {
        int nc = min(p0w + 1 + k, NPTS - 1);
        int nd = max(p0w - 8 + k, 0);
        cr[k] = bf2f(Rl[(nc - p0 + 8) * PR + 2 * 64 + l]);
        dr[k] = bf2f(Rl[(nd - p0 + 8) * PR + 3 * 64 + l]);
    }
    float m2c[10], m2d[10];
    #pragma unroll
    for (int k = 0; k < 10; ++k) { m2c[k] = fmaxf(cr[k], cr[k + 1]); m2d[k] = fmaxf(dr[k], dr[k + 1]); }
    float m4c[8], m4d[8];
    #pragma unroll
    for (int k = 0; k < 8; ++k) { m4c[k] = fmaxf(m2c[k], m2c[k + 2]); m4d[k] = fmaxf(m2d[k], m2d[k + 2]); }
    const float b1l = b1[l];

    #pragma unroll
    for (int t = 0; t < 4; ++t) {
        float mxc = fmaxf(m4c[t], m4c[t + 4]);   // max c[i+1..i+8], i = p0w+t
        float mxd = fmaxf(m4d[t], m4d[t + 4]);   // max d[i-8..i-1]
        float av = bf2f(Rl[(wv * 4 + t + 8) * PR + 0 * 64 + l]);
        float bv = bf2f(Rl[(wv * 4 + t + 8) * PR + 1 * 64 + l]);
        float mx1 = fmaxf(fmaxf(av + mxc, bv + mxd) + b1l, 0.f);
        float xi = x[(pb + p0w + t) * 64 + l];
        size_t ob = (pb + p0w + t) * 320;
        out[ob +       l] = mxv4[t];
        out[ob +  64 + l] = mxv3[t];
        out[ob + 128 + l] = mxv2[t];
        out[ob + 192 + l] = mx1;
        out[ob + 256 + l] = xi;
    }
}

extern "C" void kernel_launch(void* const* d_in, const int* in_sizes, int n_in,
                              void* d_out, int out_size, void* d_ws, size_t ws_size,
                              hipStream_t stream) {
    const float* x  = (const float*)d_in[0];
    // d_in[1] = pos : unused by the reference
    const float* W1 = (const float*)d_in[2];
    const float* b1 = (const float*)d_in[3];
    const float* W2 = (const float*)d_in[4];
    const float* b2 = (const float*)d_in[5];
    const float* W3 = (const float*)d_in[6];
    const float* b3 = (const float*)d_in[7];
    const float* W4 = (const float*)d_in[8];
    const float* b4 = (const float*)d_in[9];
    float* out = (float*)d_out;

    unsigned short* wpack = (unsigned short*)d_ws;                   // 48 KB @ 0
    unsigned short* w7    = (unsigned short*)((char*)d_ws + 65536);  // 56 KB @ 64K

    k0_wpack<<<26, 256, 0, stream>>>(W1, W2, W3, W4, wpack, w7);
    k2_fused<<<NB * (NPTS / 16), 256, 0, stream>>>(x, b1, b2, b3, b4, wpack, w7, out);
}